// Round 3
// baseline (377.666 us; speedup 1.0000x reference)
//
#include <hip/hip_runtime.h>
#include <stdint.h>

// Problem constants: B=2, S=2048, H=1024, NH=16, HD=64, K=1024
// Inputs FP32 -> one cvt pass to bf16 -> bf16 MFMA pipeline -> output FP32.

typedef __attribute__((ext_vector_type(8))) short short8;
typedef __attribute__((ext_vector_type(4))) float floatx4;
typedef __attribute__((ext_vector_type(4))) unsigned int uint4v;
typedef __attribute__((ext_vector_type(2))) unsigned int uint2v;

__device__ __forceinline__ unsigned short f2bf(float f) {          // RNE
    unsigned int u = __float_as_uint(f);
    unsigned int r = u + 0x7fffu + ((u >> 16) & 1u);
    return (unsigned short)(r >> 16);
}
// pack two fp32 -> bf16x2 dword
#if __has_builtin(__builtin_amdgcn_cvt_pk_bf16_f32)
__device__ __forceinline__ unsigned int pack_bf2(float lo, float hi) {
    auto v = __builtin_amdgcn_cvt_pk_bf16_f32(lo, hi);
    return __builtin_bit_cast(unsigned int, v);
}
#else
__device__ __forceinline__ unsigned int pack_bf2(float lo, float hi) {
    unsigned int a = __float_as_uint(lo) + 0x8000u;
    unsigned int b = __float_as_uint(hi) + 0x8000u;
    return __builtin_amdgcn_perm(b, a, 0x07060302u);
}
#endif

// raw exp2 (v_exp_f32) when available
#if __has_builtin(__builtin_amdgcn_exp2f)
#define EXP2(x) __builtin_amdgcn_exp2f(x)
#else
#define EXP2(x) exp2f(x)
#endif

// async global->LDS, 16B per lane. LDS dest: wave-uniform base + lane*16.
__device__ __forceinline__ void gl2lds16(const void* g, void* l) {
    __builtin_amdgcn_global_load_lds(
        (const __attribute__((address_space(1))) unsigned int*)g,
        (__attribute__((address_space(3))) unsigned int*)l, 16, 0, 0);
}

#define MFMA32(a, b, c) __builtin_amdgcn_mfma_f32_16x16x32_bf16((a), (b), (c), 0, 0, 0)

// ---------------------------------------------------------------------------
// One-pass prep: fp32->bf16 for hidden / w_qkv / w_out, plus mask transform
// m2 = mask*log2(e) - 10*log2(e) (fp32). Grid exactly 8196 x 256.
// ---------------------------------------------------------------------------
__global__ __launch_bounds__(256)
void cvt_all(const float* __restrict__ a, const float* __restrict__ b,
             const float* __restrict__ c, const float* __restrict__ mask,
             unsigned short* __restrict__ oa, unsigned short* __restrict__ ob,
             unsigned short* __restrict__ oc, float* __restrict__ m2b)
{
    int i = blockIdx.x * 256 + threadIdx.x;
    if (i >= 2097152) {                     // mask range: 1024 groups
        int off = i - 2097152;
        float4 v = *(const float4*)(mask + (size_t)off * 4);
        const float L2E = 1.44269504f, C2 = -14.4269504f;
        float4 w;
        w.x = fmaf(v.x, L2E, C2); w.y = fmaf(v.y, L2E, C2);
        w.z = fmaf(v.z, L2E, C2); w.w = fmaf(v.w, L2E, C2);
        *(float4*)(m2b + (size_t)off * 4) = w;
        return;
    }
    const float* src; unsigned short* dst; int off;
    if (i < 1048576)      { src = a; dst = oa; off = i; }
    else if (i < 1835008) { src = b; dst = ob; off = i - 1048576; }
    else                  { src = c; dst = oc; off = i - 1835008; }
    float4 v = *(const float4*)(src + (size_t)off * 4);
    uint2v w;
    w[0] = pack_bf2(v.x, v.y);
    w[1] = pack_bf2(v.z, v.w);
    *(uint2v*)(dst + (size_t)off * 4) = w;
}

// ---------------------------------------------------------------------------
// NT GEMM: C[M,N] = A[M,K]*B[N,K]^T, bf16 in, fp32 accum, K=1024.
// 128 x BN tile, BK=64, 4 waves (2x2) x (64 x BN/2).
// Double-buffered LDS + counted-vmcnt pipeline (T3/T4):
//   per step: raw barrier -> issue stage(t+1) into buf^1 -> vmcnt(NDMA)
//   (stage(t) landed, stage(t+1) stays in flight) -> raw barrier -> compute.
//   No __syncthreads() in the loop (it would force a vmcnt(0) drain).
// XCD-aware block swizzle.
// MODE 0: scatter bf16 to q/k ([B,NH,S,HD]) + V^T ([B,NH,HD,S'])
//         where S' is key-interleaved within 32-groups for the attn kernel:
//         k' = (k&~31) | ((k>>2)&3)<<3 | ((k>>4)&1)<<2 | (k&3).
//         q is PRE-SCALED by 0.125*log2(e) so attn can exp2 the raw MFMA out.
// MODE 1: fp32 store outf[m*N+n].
// ---------------------------------------------------------------------------
template<int MODE, int BN>
__global__ __launch_bounds__(256)
void gemm_nt(const unsigned short* __restrict__ A,
             const unsigned short* __restrict__ Bm,
             unsigned short* __restrict__ out0,
             unsigned short* __restrict__ out1,
             unsigned short* __restrict__ out2,
             float* __restrict__ outf,
             int N)
{
    constexpr int BUF = 16384 + BN * 128;        // bytes per buffer (A + B)
    __shared__ unsigned char smem[2 * BUF];
    const int K = 1024;
    const int NSTEP = 16;                        // K / 64
    const int BSL = BN / 32;
    const int tid  = threadIdx.x;
    const int wave = tid >> 6, lane = tid & 63;
    const int l15  = lane & 15, quad = lane >> 4;
    const int wm = wave >> 1, wn = wave & 1;

    int Lid = blockIdx.y * gridDim.x + blockIdx.x;
    int bm = (Lid & 7) * 4 + ((Lid >> 3) & 3);
    int bn = Lid >> 5;

    floatx4 acc[4][BSL];
#pragma unroll
    for (int i = 0; i < 4; i++)
#pragma unroll
        for (int j = 0; j < BSL; j++)
            acc[i][j] = floatx4{0.f, 0.f, 0.f, 0.f};

    int soffA[4], soffB[BSL];
#pragma unroll
    for (int l = 0; l < 4; l++) {
        int s = (wave * 4 + l) * 64 + lane;
        int row = s >> 3;
        soffA[l] = row * K + (((s & 7) ^ (row & 7)) * 8);
    }
#pragma unroll
    for (int l = 0; l < BSL; l++) {
        int s = (wave * BSL + l) * 64 + lane;
        int row = s >> 3;
        soffB[l] = row * K + (((s & 7) ^ (row & 7)) * 8);
    }

    const unsigned short* Abase = A  + (size_t)(bm * 128) * K;
    const unsigned short* Bbase = Bm + (size_t)(bn * BN) * K;

    // prologue: stage step 0 into buffer 0
#pragma unroll
    for (int l = 0; l < 4; l++)
        gl2lds16(Abase + (size_t)soffA[l], &smem[(wave * 4 + l) * 1024]);
#pragma unroll
    for (int l = 0; l < BSL; l++)
        gl2lds16(Bbase + (size_t)soffB[l], &smem[16384 + (wave * BSL + l) * 1024]);

    for (int t = 0; t < NSTEP; t++) {
        const int cb = (t & 1) * BUF;
        const int nb = ((t + 1) & 1) * BUF;
        // barrier 1: all waves done consuming buf[nb] (step t-1) -> safe to
        // overwrite. Raw barrier: no implicit vmcnt drain.
        asm volatile("" ::: "memory");
        __builtin_amdgcn_s_barrier();
        asm volatile("" ::: "memory");
        if (t + 1 < NSTEP) {
            const int k0 = (t + 1) * 64;
#pragma unroll
            for (int l = 0; l < 4; l++)
                gl2lds16(Abase + (size_t)soffA[l] + k0, &smem[nb + (wave * 4 + l) * 1024]);
#pragma unroll
            for (int l = 0; l < BSL; l++)
                gl2lds16(Bbase + (size_t)soffB[l] + k0, &smem[nb + 16384 + (wave * BSL + l) * 1024]);
            // wait for stage(t) only; stage(t+1)'s NDMA loads stay in flight
            if (BN == 128) asm volatile("s_waitcnt vmcnt(8)" ::: "memory");
            else           asm volatile("s_waitcnt vmcnt(6)" ::: "memory");
        } else {
            asm volatile("s_waitcnt vmcnt(0)" ::: "memory");
        }
        // barrier 2: cross-wave visibility of the landed tile
        __builtin_amdgcn_s_barrier();
        asm volatile("" ::: "memory");

#pragma unroll
        for (int s2 = 0; s2 < 2; s2++) {
            short8 af[4], bfr[BSL];
            int c = s2 * 4 + quad;
#pragma unroll
            for (int i = 0; i < 4; i++) {
                int row = wm * 64 + i * 16 + l15;
                af[i] = *(const short8*)(&smem[cb + row * 128 + ((c ^ (row & 7)) * 16)]);
            }
#pragma unroll
            for (int j = 0; j < BSL; j++) {
                int row = wn * (BN / 2) + j * 16 + l15;
                bfr[j] = *(const short8*)(&smem[cb + 16384 + row * 128 + ((c ^ (row & 7)) * 16)]);
            }
#pragma unroll
            for (int i = 0; i < 4; i++)
#pragma unroll
                for (int j = 0; j < BSL; j++)
                    acc[i][j] = MFMA32(af[i], bfr[j], acc[i][j]);
        }
    }

#pragma unroll
    for (int i = 0; i < 4; i++) {
#pragma unroll
        for (int j = 0; j < BSL; j++) {
            int n = bn * BN + wn * (BN / 2) + j * 16 + l15;
#pragma unroll
            for (int r = 0; r < 4; r++) {
                int m = bm * 128 + wm * 64 + i * 16 + quad * 4 + r;
                float fv = acc[i][j][r];
                if (MODE == 1) {
                    outf[(size_t)m * N + n] = fv;
                } else {
                    int t = n >> 10;            // 0=q 1=k 2=v
                    int h = (n >> 6) & 15;
                    int d = n & 63;
                    int b = m >> 11, si = m & 2047;
                    if (t == 2) {
                        // V^T with key interleave within 32-groups
                        int sip = (si & ~31) | (((si >> 2) & 3) << 3)
                                | (((si >> 4) & 1) << 2) | (si & 3);
                        out2[(((size_t)(b * 16 + h)) * 64 + d) * 2048 + sip] = f2bf(fv);
                    } else {
                        // q pre-scaled by 0.125*log2(e) (softmax fold)
                        if (t == 0) fv *= 0.18033688f;
                        size_t off = (((size_t)(b * 16 + h)) * 2048 + si) * 64 + d;
                        unsigned short* dst = (t == 0) ? out0 : out1;
                        dst[off] = f2bf(fv);
                    }
                }
            }
        }
    }
}

// ---------------------------------------------------------------------------
// Flash attention v9 — NO K/V LDS staging. K/V are L2/L3-resident (FETCH
// showed 12.4MB for 24MB logical traffic, HBM at 5%): per-lane 16B fragment
// reads go STRAIGHT from global in the exact layout we control (v_buf was
// written key-interleaved for this). Removes the DMA double-buffer, the
// vmcnt ping-pong, and the 1M LDS bank-conflict cycles; LDS shrinks to the
// 32KB epilogue reduction buffer -> 4 blocks/CU resident (whole grid), 4
// waves/SIMD: doubled TLP for this latency-bound kernel.
//  * full-K=32 PV via key-interleaved V^T (one un-padded MFMA per dt)
//  * mask addend in QK MFMA C-init; Q pre-scaled by 0.125*log2e -> exp2
//    directly on MFMA output.
//  * load order kf -> mf -> vf so the compiler's counted vmcnt hides vf
//    latency under QK+exp; kf latency hidden by TLP.
// ---------------------------------------------------------------------------
__global__ __launch_bounds__(256, 4)
void attn_kernel(const unsigned short* __restrict__ Qb,
                 const unsigned short* __restrict__ Kb,
                 const unsigned short* __restrict__ VbT,
                 const float* __restrict__ m2b,
                 const float* __restrict__ gateb,
                 unsigned short* __restrict__ ctx)
{
    __shared__ unsigned char smem[32768];
    const int S = 2048;
    const int tid  = threadIdx.x;
    const int wave = tid >> 6, lane = tid & 63;
    const int l15  = lane & 15, quad = lane >> 4;

    int Lid = blockIdx.y * gridDim.x + blockIdx.x;
    int bh = (Lid & 7) * 4 + ((Lid >> 3) & 3);
    int qc = Lid >> 5;
    const int b = bh >> 4, h = bh & 15;
    const int q0 = qc * 64;

    const size_t headoff = (size_t)bh * S * 64;
    const unsigned short* Qh  = Qb  + headoff;   // [S][64] (pre-scaled)
    const unsigned short* Kh  = Kb  + headoff;   // [S][64]
    const unsigned short* VhT = VbT + headoff;   // [64][S'] key-interleaved
    const float* m2p = m2b + (size_t)b * S;

    // per-lane global fragment bases (replace LDS staging):
    // kf[t][s2] lane reads K[kb + t*16 + l15][s2*32 + quad*8 .. +8)
    // vf[dt]    lane reads V^T[dt*16 + l15][kb' + quad*8 .. +8)
    const unsigned short* kp = Kh  + (size_t)l15 * 64   + quad * 8;
    const unsigned short* vp = VhT + (size_t)l15 * 2048 + quad * 8;

    // Q B-frags: aq[sub][s2] = Q[q=q0+sub*16+l15][k=s2*32+quad*8+j]
    short8 aq[4][2];
#pragma unroll
    for (int sub = 0; sub < 4; sub++)
#pragma unroll
        for (int s2 = 0; s2 < 2; s2++)
            aq[sub][s2] = *(const short8*)(Qh + (size_t)(q0 + sub * 16 + l15) * 64 + s2 * 32 + quad * 8);

    floatx4 o[4][4];                 // O^T partial [sub][dt]
    floatx4 lq[4];                   // l partial [sub] (all rows equal)
#pragma unroll
    for (int sub = 0; sub < 4; sub++) {
        lq[sub] = floatx4{0.f, 0.f, 0.f, 0.f};
#pragma unroll
        for (int dt = 0; dt < 4; dt++) o[sub][dt] = floatx4{0.f, 0.f, 0.f, 0.f};
    }

    const uint4v onesu = {0x3F803F80u, 0x3F803F80u, 0x3F803F80u, 0x3F803F80u};
    const short8 ONES = __builtin_bit_cast(short8, onesu);

    for (int i = 0; i < 16; i++) {
        const int kb = (wave + 4 * i) * 32;
        // K frags first (needed by QK)
        short8 kf[2][2];
#pragma unroll
        for (int t = 0; t < 2; t++)
#pragma unroll
            for (int s2 = 0; s2 < 2; s2++)
                kf[t][s2] = *(const short8*)(kp + (size_t)kb * 64 + t * 1024 + s2 * 32);
        // mask addends (QK C-init: C/D row == key == quad*4+r)
        floatx4 mf[2];
#pragma unroll
        for (int t = 0; t < 2; t++)
            mf[t] = *(const floatx4*)(m2p + kb + t * 16 + quad * 4);
        // V frags last (needed only by PV; latency hides under QK+exp)
        short8 vf[4];
#pragma unroll
        for (int dt = 0; dt < 4; dt++)
            vf[dt] = *(const short8*)(vp + (size_t)dt * 32768 + kb);

#pragma unroll
        for (int sub = 0; sub < 4; sub++) {
            // S^T = K·Q^T, C init = mask addend (log2 domain, fixed-max -10)
            floatx4 st0 = MFMA32(kf[0][0], aq[sub][0], mf[0]);
            floatx4 st1 = MFMA32(kf[1][0], aq[sub][0], mf[1]);
            st0 = MFMA32(kf[0][1], aq[sub][1], st0);
            st1 = MFMA32(kf[1][1], aq[sub][1], st1);
            // exp directly on MFMA output (Q pre-scaled, mask in C-init)
            float e00 = EXP2(st0[0]), e01 = EXP2(st0[1]);
            float e02 = EXP2(st0[2]), e03 = EXP2(st0[3]);
            float e10 = EXP2(st1[0]), e11 = EXP2(st1[1]);
            float e12 = EXP2(st1[2]), e13 = EXP2(st1[3]);
            // P packed across BOTH key-tiles in interleave order
            uint4v pu = {pack_bf2(e00, e01), pack_bf2(e02, e03),
                         pack_bf2(e10, e11), pack_bf2(e12, e13)};
            short8 pf = __builtin_bit_cast(short8, pu);
            // full-K=32 PV: one un-padded MFMA per dt + one l-row MFMA
#pragma unroll
            for (int dt = 0; dt < 4; dt++)
                o[sub][dt] = MFMA32(vf[dt], pf, o[sub][dt]);
            lq[sub] = MFMA32(ONES, pf, lq[sub]);
        }
    }

    // cross-wave reduction: wave w ends owning sub = w
    floatx4 ro[4];
#pragma unroll
    for (int ph = 0; ph < 2; ph++) {
        __syncthreads();
#pragma unroll
        for (int sub = 0; sub < 4; sub++)
#pragma unroll
            for (int d2 = 0; d2 < 2; d2++)
                *(floatx4*)(&smem[(((wave * 4 + sub) * 2 + d2) * 64 + lane) * 16]) = o[sub][ph * 2 + d2];
        __syncthreads();
#pragma unroll
        for (int d2 = 0; d2 < 2; d2++) {
            floatx4 acc = floatx4{0.f, 0.f, 0.f, 0.f};
#pragma unroll
            for (int w2 = 0; w2 < 4; w2++)
                acc += *(const floatx4*)(&smem[(((w2 * 4 + wave) * 2 + d2) * 64 + lane) * 16]);
            ro[ph * 2 + d2] = acc;
        }
    }
    __syncthreads();
#pragma unroll
    for (int sub = 0; sub < 4; sub++)
        *(floatx4*)(&smem[((wave * 4 + sub) * 64 + lane) * 16]) = lq[sub];
    __syncthreads();
    floatx4 rl = floatx4{0.f, 0.f, 0.f, 0.f};
#pragma unroll
    for (int w2 = 0; w2 < 4; w2++)
        rl += *(const floatx4*)(&smem[((w2 * 4 + wave) * 64 + lane) * 16]);

    // epilogue: this wave writes q = q0 + wave*16 + l15, all dt
    float iv = gateb[h] / rl[0];
    size_t base = ((size_t)(b * 2048 + q0 + wave * 16 + l15)) * 1024 + h * 64 + quad * 4;
#pragma unroll
    for (int dt = 0; dt < 4; dt++) {
        uint2v w;
        w[0] = pack_bf2(ro[dt][0] * iv, ro[dt][1] * iv);
        w[1] = pack_bf2(ro[dt][2] * iv, ro[dt][3] * iv);
        *(uint2v*)(ctx + base + dt * 16) = w;
    }
}

// ---------------------------------------------------------------------------
extern "C" void kernel_launch(void* const* d_in, const int* in_sizes, int n_in,
                              void* d_out, int out_size, void* d_ws, size_t ws_size,
                              hipStream_t stream)
{
    const float* hidden = (const float*)d_in[0]; // [2,2048,1024] fp32
    const float* mask   = (const float*)d_in[1]; // [2,1,1,2048]  fp32
    const float* w_qkv  = (const float*)d_in[2]; // [3072,1024]   fp32
    const float* w_out  = (const float*)d_in[3]; // [1024,1024]   fp32
    const float* gate   = (const float*)d_in[4]; // [16]          fp32
    float* out = (float*)d_out;                  // [2,2048,1024] fp32

    unsigned short* q_buf = (unsigned short*)d_ws;   // [2,16,2048,64] bf16 (pre-scaled)
    unsigned short* k_buf = q_buf + 4194304;         // [2,16,2048,64]
    unsigned short* v_buf = k_buf + 4194304;         // [2,16,64,2048] (V^T, interleaved)
    unsigned short* c_buf = v_buf + 4194304;         // [2,2048,1024]  bf16
    unsigned short* h_bf  = c_buf + 4194304;         // hidden bf16
    unsigned short* wq_bf = h_bf  + 4194304;         // w_qkv bf16
    unsigned short* wo_bf = wq_bf + 3145728;         // w_out bf16
    float* m2_buf = (float*)(wo_bf + 1048576);       // [2,2048] fp32

    // one-pass prep: fp32->bf16 converts + mask transform
    cvt_all<<<8196, 256, 0, stream>>>(hidden, w_qkv, w_out, mask,
                                      h_bf, wq_bf, wo_bf, m2_buf);

    // QKV projection, scatter q(pre-scaled)/k/V^T(interleaved)
    gemm_nt<0, 128><<<dim3(24, 32), 256, 0, stream>>>(h_bf, wq_bf, q_buf, k_buf, v_buf, nullptr, 3072);
    // fused flash attention + gate -> ctx bf16 (64-q blocks, grid 1024)
    attn_kernel<<<dim3(32, 32), 256, 0, stream>>>(q_buf, k_buf, v_buf, m2_buf, gate, c_buf);
    // output projection -> out fp32 (grid 16x32, 128x64 tiles)
    gemm_nt<1, 64><<<dim3(16, 32), 256, 0, stream>>>(c_buf, wo_bf, nullptr, nullptr, nullptr, out, 1024);
}

// Round 4
// 371.266 us; speedup vs baseline: 1.0172x; 1.0172x over previous
//
#include <hip/hip_runtime.h>
#include <stdint.h>

// Problem constants: B=2, S=2048, H=1024, NH=16, HD=64, K=1024
// Inputs FP32 -> one cvt pass to bf16 -> bf16 MFMA pipeline -> output FP32.

typedef __attribute__((ext_vector_type(8))) short short8;
typedef __attribute__((ext_vector_type(4))) float floatx4;
typedef __attribute__((ext_vector_type(4))) unsigned int uint4v;
typedef __attribute__((ext_vector_type(2))) unsigned int uint2v;

__device__ __forceinline__ unsigned short f2bf(float f) {          // RNE
    unsigned int u = __float_as_uint(f);
    unsigned int r = u + 0x7fffu + ((u >> 16) & 1u);
    return (unsigned short)(r >> 16);
}
// pack two fp32 -> bf16x2 dword
#if __has_builtin(__builtin_amdgcn_cvt_pk_bf16_f32)
__device__ __forceinline__ unsigned int pack_bf2(float lo, float hi) {
    auto v = __builtin_amdgcn_cvt_pk_bf16_f32(lo, hi);
    return __builtin_bit_cast(unsigned int, v);
}
#else
__device__ __forceinline__ unsigned int pack_bf2(float lo, float hi) {
    unsigned int a = __float_as_uint(lo) + 0x8000u;
    unsigned int b = __float_as_uint(hi) + 0x8000u;
    return __builtin_amdgcn_perm(b, a, 0x07060302u);
}
#endif

// raw exp2 (v_exp_f32) when available
#if __has_builtin(__builtin_amdgcn_exp2f)
#define EXP2(x) __builtin_amdgcn_exp2f(x)
#else
#define EXP2(x) exp2f(x)
#endif

// async global->LDS, 16B per lane. LDS dest: wave-uniform base + lane*16.
__device__ __forceinline__ void gl2lds16(const void* g, void* l) {
    __builtin_amdgcn_global_load_lds(
        (const __attribute__((address_space(1))) unsigned int*)g,
        (__attribute__((address_space(3))) unsigned int*)l, 16, 0, 0);
}

#define MFMA32(a, b, c) __builtin_amdgcn_mfma_f32_16x16x32_bf16((a), (b), (c), 0, 0, 0)

// ---------------------------------------------------------------------------
// One-pass prep: fp32->bf16 for hidden / w_qkv / w_out, plus mask transform
// m2 = mask*log2(e) - 10*log2(e) (fp32). Grid exactly 8196 x 256.
// ---------------------------------------------------------------------------
__global__ __launch_bounds__(256)
void cvt_all(const float* __restrict__ a, const float* __restrict__ b,
             const float* __restrict__ c, const float* __restrict__ mask,
             unsigned short* __restrict__ oa, unsigned short* __restrict__ ob,
             unsigned short* __restrict__ oc, float* __restrict__ m2b)
{
    int i = blockIdx.x * 256 + threadIdx.x;
    if (i >= 2097152) {                     // mask range: 1024 groups
        int off = i - 2097152;
        float4 v = *(const float4*)(mask + (size_t)off * 4);
        const float L2E = 1.44269504f, C2 = -14.4269504f;
        float4 w;
        w.x = fmaf(v.x, L2E, C2); w.y = fmaf(v.y, L2E, C2);
        w.z = fmaf(v.z, L2E, C2); w.w = fmaf(v.w, L2E, C2);
        *(float4*)(m2b + (size_t)off * 4) = w;
        return;
    }
    const float* src; unsigned short* dst; int off;
    if (i < 1048576)      { src = a; dst = oa; off = i; }
    else if (i < 1835008) { src = b; dst = ob; off = i - 1048576; }
    else                  { src = c; dst = oc; off = i - 1835008; }
    float4 v = *(const float4*)(src + (size_t)off * 4);
    uint2v w;
    w[0] = pack_bf2(v.x, v.y);
    w[1] = pack_bf2(v.z, v.w);
    *(uint2v*)(dst + (size_t)off * 4) = w;
}

// ---------------------------------------------------------------------------
// NT GEMM: C[M,N] = A[M,K]*B[N,K]^T, bf16 in, fp32 accum, K=1024.
// 128 x BN tile, BK=64, 4 waves (2x2) x (64 x BN/2).
// Double-buffered LDS + counted-vmcnt pipeline (T3/T4):
//   per step: raw barrier -> issue stage(t+1) into buf^1 -> vmcnt(NDMA)
//   (stage(t) landed, stage(t+1) stays in flight) -> raw barrier -> compute.
//   No __syncthreads() in the loop (it would force a vmcnt(0) drain).
// XCD-aware block swizzle.
// MODE 0: scatter bf16 to q/k ([B,NH,S,HD]) + V^T ([B,NH,HD,S'])
//         where S' is key-interleaved within 32-groups for the attn kernel:
//         k' = (k&~31) | ((k>>2)&3)<<3 | ((k>>4)&1)<<2 | (k&3).
//         q is PRE-SCALED by 0.125*log2(e) so attn can exp2 the raw MFMA out.
// MODE 1: fp32 store outf[m*N+n].
// ---------------------------------------------------------------------------
template<int MODE, int BN>
__global__ __launch_bounds__(256)
void gemm_nt(const unsigned short* __restrict__ A,
             const unsigned short* __restrict__ Bm,
             unsigned short* __restrict__ out0,
             unsigned short* __restrict__ out1,
             unsigned short* __restrict__ out2,
             float* __restrict__ outf,
             int N)
{
    constexpr int BUF = 16384 + BN * 128;        // bytes per buffer (A + B)
    __shared__ unsigned char smem[2 * BUF];
    const int K = 1024;
    const int NSTEP = 16;                        // K / 64
    const int BSL = BN / 32;
    const int tid  = threadIdx.x;
    const int wave = tid >> 6, lane = tid & 63;
    const int l15  = lane & 15, quad = lane >> 4;
    const int wm = wave >> 1, wn = wave & 1;

    int Lid = blockIdx.y * gridDim.x + blockIdx.x;
    int bm = (Lid & 7) * 4 + ((Lid >> 3) & 3);
    int bn = Lid >> 5;

    floatx4 acc[4][BSL];
#pragma unroll
    for (int i = 0; i < 4; i++)
#pragma unroll
        for (int j = 0; j < BSL; j++)
            acc[i][j] = floatx4{0.f, 0.f, 0.f, 0.f};

    int soffA[4], soffB[BSL];
#pragma unroll
    for (int l = 0; l < 4; l++) {
        int s = (wave * 4 + l) * 64 + lane;
        int row = s >> 3;
        soffA[l] = row * K + (((s & 7) ^ (row & 7)) * 8);
    }
#pragma unroll
    for (int l = 0; l < BSL; l++) {
        int s = (wave * BSL + l) * 64 + lane;
        int row = s >> 3;
        soffB[l] = row * K + (((s & 7) ^ (row & 7)) * 8);
    }

    const unsigned short* Abase = A  + (size_t)(bm * 128) * K;
    const unsigned short* Bbase = Bm + (size_t)(bn * BN) * K;

    // prologue: stage step 0 into buffer 0
#pragma unroll
    for (int l = 0; l < 4; l++)
        gl2lds16(Abase + (size_t)soffA[l], &smem[(wave * 4 + l) * 1024]);
#pragma unroll
    for (int l = 0; l < BSL; l++)
        gl2lds16(Bbase + (size_t)soffB[l], &smem[16384 + (wave * BSL + l) * 1024]);

    for (int t = 0; t < NSTEP; t++) {
        const int cb = (t & 1) * BUF;
        const int nb = ((t + 1) & 1) * BUF;
        // barrier 1: all waves done consuming buf[nb] (step t-1) -> safe to
        // overwrite. Raw barrier: no implicit vmcnt drain.
        asm volatile("" ::: "memory");
        __builtin_amdgcn_s_barrier();
        asm volatile("" ::: "memory");
        if (t + 1 < NSTEP) {
            const int k0 = (t + 1) * 64;
#pragma unroll
            for (int l = 0; l < 4; l++)
                gl2lds16(Abase + (size_t)soffA[l] + k0, &smem[nb + (wave * 4 + l) * 1024]);
#pragma unroll
            for (int l = 0; l < BSL; l++)
                gl2lds16(Bbase + (size_t)soffB[l] + k0, &smem[nb + 16384 + (wave * BSL + l) * 1024]);
            // wait for stage(t) only; stage(t+1)'s NDMA loads stay in flight
            if (BN == 128) asm volatile("s_waitcnt vmcnt(8)" ::: "memory");
            else           asm volatile("s_waitcnt vmcnt(6)" ::: "memory");
        } else {
            asm volatile("s_waitcnt vmcnt(0)" ::: "memory");
        }
        // barrier 2: cross-wave visibility of the landed tile
        __builtin_amdgcn_s_barrier();
        asm volatile("" ::: "memory");

#pragma unroll
        for (int s2 = 0; s2 < 2; s2++) {
            short8 af[4], bfr[BSL];
            int c = s2 * 4 + quad;
#pragma unroll
            for (int i = 0; i < 4; i++) {
                int row = wm * 64 + i * 16 + l15;
                af[i] = *(const short8*)(&smem[cb + row * 128 + ((c ^ (row & 7)) * 16)]);
            }
#pragma unroll
            for (int j = 0; j < BSL; j++) {
                int row = wn * (BN / 2) + j * 16 + l15;
                bfr[j] = *(const short8*)(&smem[cb + 16384 + row * 128 + ((c ^ (row & 7)) * 16)]);
            }
#pragma unroll
            for (int i = 0; i < 4; i++)
#pragma unroll
                for (int j = 0; j < BSL; j++)
                    acc[i][j] = MFMA32(af[i], bfr[j], acc[i][j]);
        }
    }

#pragma unroll
    for (int i = 0; i < 4; i++) {
#pragma unroll
        for (int j = 0; j < BSL; j++) {
            int n = bn * BN + wn * (BN / 2) + j * 16 + l15;
#pragma unroll
            for (int r = 0; r < 4; r++) {
                int m = bm * 128 + wm * 64 + i * 16 + quad * 4 + r;
                float fv = acc[i][j][r];
                if (MODE == 1) {
                    outf[(size_t)m * N + n] = fv;
                } else {
                    int t = n >> 10;            // 0=q 1=k 2=v
                    int h = (n >> 6) & 15;
                    int d = n & 63;
                    int b = m >> 11, si = m & 2047;
                    if (t == 2) {
                        // V^T with key interleave within 32-groups
                        int sip = (si & ~31) | (((si >> 2) & 3) << 3)
                                | (((si >> 4) & 1) << 2) | (si & 3);
                        out2[(((size_t)(b * 16 + h)) * 64 + d) * 2048 + sip] = f2bf(fv);
                    } else {
                        // q pre-scaled by 0.125*log2(e) (softmax fold)
                        if (t == 0) fv *= 0.18033688f;
                        size_t off = (((size_t)(b * 16 + h)) * 2048 + si) * 64 + d;
                        unsigned short* dst = (t == 0) ? out0 : out1;
                        dst[off] = f2bf(fv);
                    }
                }
            }
        }
    }
}

// ---------------------------------------------------------------------------
// Flash attention v10 — q-split waves, zero LDS, zero barriers.
// Round-2 lesson: key-split + direct-global needs o[4][4]=64 acc VGPRs and
// spilled catastrophically (372MB scratch writes). Fix: each wave owns 16
// q-rows (sub == wave) and iterates ALL 2048 keys. Accumulator shrinks to
// o[4] (16 VGPRs), the softmax denominator is complete per-wave, so the
// cross-wave LDS reduction + barriers are GONE. LDS = 0 -> whole grid
// resident (4 blocks/CU, 4 waves/SIMD). All 4 waves of a block read the
// same K/V chunk -> L1-served (8KB chunk in 32KB L1).
//  * K/V per-lane 16B fragment reads straight from global in the layout we
//    control (v_buf written key-interleaved for full-K=32 PV).
//  * mask addend in QK MFMA C-init; Q pre-scaled by 0.125*log2e -> exp2
//    directly on MFMA output.
//  * load order kf -> mf -> vf so vf latency hides under QK+exp.
// Live set ~100 VGPR: fits the (256,4) cap of 128 with no spills.
// ---------------------------------------------------------------------------
__global__ __launch_bounds__(256, 4)
void attn_kernel(const unsigned short* __restrict__ Qb,
                 const unsigned short* __restrict__ Kb,
                 const unsigned short* __restrict__ VbT,
                 const float* __restrict__ m2b,
                 const float* __restrict__ gateb,
                 unsigned short* __restrict__ ctx)
{
    const int S = 2048;
    const int tid  = threadIdx.x;
    const int wave = tid >> 6, lane = tid & 63;
    const int l15  = lane & 15, quad = lane >> 4;

    int Lid = blockIdx.y * gridDim.x + blockIdx.x;
    int bh = (Lid & 7) * 4 + ((Lid >> 3) & 3);
    int qc = Lid >> 5;
    const int b = bh >> 4, h = bh & 15;
    const int q0 = qc * 64 + wave * 16;          // this wave's 16 q-rows

    const size_t headoff = (size_t)bh * S * 64;
    const unsigned short* Qh  = Qb  + headoff;   // [S][64] (pre-scaled)
    const unsigned short* Kh  = Kb  + headoff;   // [S][64]
    const unsigned short* VhT = VbT + headoff;   // [64][S'] key-interleaved
    const float* m2p = m2b + (size_t)b * S;

    // per-lane global fragment bases:
    // kf[t][s2]: K[kb + t*16 + l15][s2*32 + quad*8 .. +8)
    // vf[dt]   : V^T[dt*16 + l15][kb' + quad*8 .. +8)  (interleaved keys)
    const unsigned short* kp = Kh  + (size_t)l15 * 64   + quad * 8;
    const unsigned short* vp = VhT + (size_t)l15 * 2048 + quad * 8;

    // Q B-frags for this wave's rows: aq[s2] = Q[q0+l15][s2*32+quad*8+j]
    short8 aq[2];
#pragma unroll
    for (int s2 = 0; s2 < 2; s2++)
        aq[s2] = *(const short8*)(Qh + (size_t)(q0 + l15) * 64 + s2 * 32 + quad * 8);

    floatx4 o[4];                    // O^T partial [dt]  (d = dt*16+quad*4+r)
    floatx4 lq = floatx4{0.f, 0.f, 0.f, 0.f};
#pragma unroll
    for (int dt = 0; dt < 4; dt++) o[dt] = floatx4{0.f, 0.f, 0.f, 0.f};

    const uint4v onesu = {0x3F803F80u, 0x3F803F80u, 0x3F803F80u, 0x3F803F80u};
    const short8 ONES = __builtin_bit_cast(short8, onesu);

    for (int i = 0; i < 64; i++) {
        const int kb = i * 32;
        // K frags first (needed by QK)
        short8 kf[2][2];
#pragma unroll
        for (int t = 0; t < 2; t++)
#pragma unroll
            for (int s2 = 0; s2 < 2; s2++)
                kf[t][s2] = *(const short8*)(kp + (size_t)kb * 64 + t * 1024 + s2 * 32);
        // mask addends (QK C-init: C/D row == key == quad*4+r)
        floatx4 mf[2];
#pragma unroll
        for (int t = 0; t < 2; t++)
            mf[t] = *(const floatx4*)(m2p + kb + t * 16 + quad * 4);
        // V frags last (needed only by PV; latency hides under QK+exp)
        short8 vf[4];
#pragma unroll
        for (int dt = 0; dt < 4; dt++)
            vf[dt] = *(const short8*)(vp + (size_t)dt * 32768 + kb);

        // S^T = K·Q^T, C init = mask addend (log2 domain, fixed-max -10)
        floatx4 st0 = MFMA32(kf[0][0], aq[0], mf[0]);
        floatx4 st1 = MFMA32(kf[1][0], aq[0], mf[1]);
        st0 = MFMA32(kf[0][1], aq[1], st0);
        st1 = MFMA32(kf[1][1], aq[1], st1);
        // exp directly on MFMA output (Q pre-scaled, mask in C-init)
        float e00 = EXP2(st0[0]), e01 = EXP2(st0[1]);
        float e02 = EXP2(st0[2]), e03 = EXP2(st0[3]);
        float e10 = EXP2(st1[0]), e11 = EXP2(st1[1]);
        float e12 = EXP2(st1[2]), e13 = EXP2(st1[3]);
        // P packed across BOTH key-tiles in interleave order
        uint4v pu = {pack_bf2(e00, e01), pack_bf2(e02, e03),
                     pack_bf2(e10, e11), pack_bf2(e12, e13)};
        short8 pf = __builtin_bit_cast(short8, pu);
        // full-K=32 PV: one un-padded MFMA per dt + one l-row MFMA
#pragma unroll
        for (int dt = 0; dt < 4; dt++)
            o[dt] = MFMA32(vf[dt], pf, o[dt]);
        lq = MFMA32(ONES, pf, lq);
    }

    // epilogue: wave-complete softmax; lane writes q = q0 + l15, d block dt
    float iv = gateb[h] / lq[0];
    size_t base = ((size_t)(b * 2048 + q0 + l15)) * 1024 + h * 64 + quad * 4;
#pragma unroll
    for (int dt = 0; dt < 4; dt++) {
        uint2v w;
        w[0] = pack_bf2(o[dt][0] * iv, o[dt][1] * iv);
        w[1] = pack_bf2(o[dt][2] * iv, o[dt][3] * iv);
        *(uint2v*)(ctx + base + dt * 16) = w;
    }
}

// ---------------------------------------------------------------------------
extern "C" void kernel_launch(void* const* d_in, const int* in_sizes, int n_in,
                              void* d_out, int out_size, void* d_ws, size_t ws_size,
                              hipStream_t stream)
{
    const float* hidden = (const float*)d_in[0]; // [2,2048,1024] fp32
    const float* mask   = (const float*)d_in[1]; // [2,1,1,2048]  fp32
    const float* w_qkv  = (const float*)d_in[2]; // [3072,1024]   fp32
    const float* w_out  = (const float*)d_in[3]; // [1024,1024]   fp32
    const float* gate   = (const float*)d_in[4]; // [16]          fp32
    float* out = (float*)d_out;                  // [2,2048,1024] fp32

    unsigned short* q_buf = (unsigned short*)d_ws;   // [2,16,2048,64] bf16 (pre-scaled)
    unsigned short* k_buf = q_buf + 4194304;         // [2,16,2048,64]
    unsigned short* v_buf = k_buf + 4194304;         // [2,16,64,2048] (V^T, interleaved)
    unsigned short* c_buf = v_buf + 4194304;         // [2,2048,1024]  bf16
    unsigned short* h_bf  = c_buf + 4194304;         // hidden bf16
    unsigned short* wq_bf = h_bf  + 4194304;         // w_qkv bf16
    unsigned short* wo_bf = wq_bf + 3145728;         // w_out bf16
    float* m2_buf = (float*)(wo_bf + 1048576);       // [2,2048] fp32

    // one-pass prep: fp32->bf16 converts + mask transform
    cvt_all<<<8196, 256, 0, stream>>>(hidden, w_qkv, w_out, mask,
                                      h_bf, wq_bf, wo_bf, m2_buf);

    // QKV projection, scatter q(pre-scaled)/k/V^T(interleaved)
    gemm_nt<0, 128><<<dim3(24, 32), 256, 0, stream>>>(h_bf, wq_bf, q_buf, k_buf, v_buf, nullptr, 3072);
    // fused flash attention + gate -> ctx bf16 (64-q blocks, grid 1024)
    attn_kernel<<<dim3(32, 32), 256, 0, stream>>>(q_buf, k_buf, v_buf, m2_buf, gate, c_buf);
    // output projection -> out fp32 (grid 16x32, 128x64 tiles)
    gemm_nt<1, 64><<<dim3(16, 32), 256, 0, stream>>>(c_buf, wo_bf, nullptr, nullptr, nullptr, out, 1024);
}

// Round 7
// 180.182 us; speedup vs baseline: 2.0960x; 2.0605x over previous
//
#include <hip/hip_runtime.h>
#include <stdint.h>

// Problem constants: B=2, S=2048, H=1024, NH=16, HD=64, K=1024
// Inputs FP32 -> one cvt pass to bf16 -> bf16 MFMA pipeline -> output FP32.

typedef __attribute__((ext_vector_type(8))) short short8;
typedef __attribute__((ext_vector_type(4))) float floatx4;
typedef __attribute__((ext_vector_type(4))) unsigned int uint4v;
typedef __attribute__((ext_vector_type(2))) unsigned int uint2v;

__device__ __forceinline__ unsigned short f2bf(float f) {          // RNE
    unsigned int u = __float_as_uint(f);
    unsigned int r = u + 0x7fffu + ((u >> 16) & 1u);
    return (unsigned short)(r >> 16);
}
// pack two fp32 -> bf16x2 dword
#if __has_builtin(__builtin_amdgcn_cvt_pk_bf16_f32)
__device__ __forceinline__ unsigned int pack_bf2(float lo, float hi) {
    auto v = __builtin_amdgcn_cvt_pk_bf16_f32(lo, hi);
    return __builtin_bit_cast(unsigned int, v);
}
#else
__device__ __forceinline__ unsigned int pack_bf2(float lo, float hi) {
    unsigned int a = __float_as_uint(lo) + 0x8000u;
    unsigned int b = __float_as_uint(hi) + 0x8000u;
    return __builtin_amdgcn_perm(b, a, 0x07060302u);
}
#endif

// raw exp2 (v_exp_f32) when available
#if __has_builtin(__builtin_amdgcn_exp2f)
#define EXP2(x) __builtin_amdgcn_exp2f(x)
#else
#define EXP2(x) exp2f(x)
#endif

// async global->LDS, 16B per lane. LDS dest: wave-uniform base + lane*16.
__device__ __forceinline__ void gl2lds16(const void* g, void* l) {
    __builtin_amdgcn_global_load_lds(
        (const __attribute__((address_space(1))) unsigned int*)g,
        (__attribute__((address_space(3))) unsigned int*)l, 16, 0, 0);
}

#define MFMA32(a, b, c) __builtin_amdgcn_mfma_f32_16x16x32_bf16((a), (b), (c), 0, 0, 0)

// ---------------------------------------------------------------------------
// One-pass prep: fp32->bf16 for hidden / w_qkv / w_out, plus mask transform
// m2 = mask*log2(e) - 10*log2(e) (fp32). Grid exactly 8196 x 256.
// ---------------------------------------------------------------------------
__global__ __launch_bounds__(256)
void cvt_all(const float* __restrict__ a, const float* __restrict__ b,
             const float* __restrict__ c, const float* __restrict__ mask,
             unsigned short* __restrict__ oa, unsigned short* __restrict__ ob,
             unsigned short* __restrict__ oc, float* __restrict__ m2b)
{
    int i = blockIdx.x * 256 + threadIdx.x;
    if (i >= 2097152) {                     // mask range: 1024 groups
        int off = i - 2097152;
        float4 v = *(const float4*)(mask + (size_t)off * 4);
        const float L2E = 1.44269504f, C2 = -14.4269504f;
        float4 w;
        w.x = fmaf(v.x, L2E, C2); w.y = fmaf(v.y, L2E, C2);
        w.z = fmaf(v.z, L2E, C2); w.w = fmaf(v.w, L2E, C2);
        *(float4*)(m2b + (size_t)off * 4) = w;
        return;
    }
    const float* src; unsigned short* dst; int off;
    if (i < 1048576)      { src = a; dst = oa; off = i; }
    else if (i < 1835008) { src = b; dst = ob; off = i - 1048576; }
    else                  { src = c; dst = oc; off = i - 1835008; }
    float4 v = *(const float4*)(src + (size_t)off * 4);
    uint2v w;
    w[0] = pack_bf2(v.x, v.y);
    w[1] = pack_bf2(v.z, v.w);
    *(uint2v*)(dst + (size_t)off * 4) = w;
}

// ---------------------------------------------------------------------------
// NT GEMM: C[M,N] = A[M,K]*B[N,K]^T, bf16 in, fp32 accum, K=1024.
// 128 x BN tile, BK=64, 4 waves (2x2) x (64 x BN/2).
// Double-buffered LDS + counted-vmcnt pipeline (T3/T4):
//   per step: raw barrier -> issue stage(t+1) into buf^1 -> vmcnt(NDMA)
//   (stage(t) landed, stage(t+1) stays in flight) -> raw barrier -> compute.
//   No __syncthreads() in the loop (it would force a vmcnt(0) drain).
// XCD-aware block swizzle.
// MODE 0: scatter bf16 to q/k ([B,NH,S,HD]) + V^T ([B,NH,HD,S'])
//         where S' is key-interleaved within 32-groups for the attn kernel:
//         k' = (k&~31) | ((k>>2)&3)<<3 | ((k>>4)&1)<<2 | (k&3).
//         q is PRE-SCALED by 0.125*log2(e) so attn can exp2 the raw MFMA out.
// MODE 1: fp32 store outf[m*N+n].
// ---------------------------------------------------------------------------
template<int MODE, int BN>
__global__ __launch_bounds__(256)
void gemm_nt(const unsigned short* __restrict__ A,
             const unsigned short* __restrict__ Bm,
             unsigned short* __restrict__ out0,
             unsigned short* __restrict__ out1,
             unsigned short* __restrict__ out2,
             float* __restrict__ outf,
             int N)
{
    constexpr int BUF = 16384 + BN * 128;        // bytes per buffer (A + B)
    __shared__ unsigned char smem[2 * BUF];
    const int K = 1024;
    const int NSTEP = 16;                        // K / 64
    const int BSL = BN / 32;
    const int tid  = threadIdx.x;
    const int wave = tid >> 6, lane = tid & 63;
    const int l15  = lane & 15, quad = lane >> 4;
    const int wm = wave >> 1, wn = wave & 1;

    int Lid = blockIdx.y * gridDim.x + blockIdx.x;
    int bm = (Lid & 7) * 4 + ((Lid >> 3) & 3);
    int bn = Lid >> 5;

    floatx4 acc[4][BSL];
#pragma unroll
    for (int i = 0; i < 4; i++)
#pragma unroll
        for (int j = 0; j < BSL; j++)
            acc[i][j] = floatx4{0.f, 0.f, 0.f, 0.f};

    int soffA[4], soffB[BSL];
#pragma unroll
    for (int l = 0; l < 4; l++) {
        int s = (wave * 4 + l) * 64 + lane;
        int row = s >> 3;
        soffA[l] = row * K + (((s & 7) ^ (row & 7)) * 8);
    }
#pragma unroll
    for (int l = 0; l < BSL; l++) {
        int s = (wave * BSL + l) * 64 + lane;
        int row = s >> 3;
        soffB[l] = row * K + (((s & 7) ^ (row & 7)) * 8);
    }

    const unsigned short* Abase = A  + (size_t)(bm * 128) * K;
    const unsigned short* Bbase = Bm + (size_t)(bn * BN) * K;

    // prologue: stage step 0 into buffer 0
#pragma unroll
    for (int l = 0; l < 4; l++)
        gl2lds16(Abase + (size_t)soffA[l], &smem[(wave * 4 + l) * 1024]);
#pragma unroll
    for (int l = 0; l < BSL; l++)
        gl2lds16(Bbase + (size_t)soffB[l], &smem[16384 + (wave * BSL + l) * 1024]);

    for (int t = 0; t < NSTEP; t++) {
        const int cb = (t & 1) * BUF;
        const int nb = ((t + 1) & 1) * BUF;
        // barrier 1: all waves done consuming buf[nb] (step t-1) -> safe to
        // overwrite. Raw barrier: no implicit vmcnt drain.
        asm volatile("" ::: "memory");
        __builtin_amdgcn_s_barrier();
        asm volatile("" ::: "memory");
        if (t + 1 < NSTEP) {
            const int k0 = (t + 1) * 64;
#pragma unroll
            for (int l = 0; l < 4; l++)
                gl2lds16(Abase + (size_t)soffA[l] + k0, &smem[nb + (wave * 4 + l) * 1024]);
#pragma unroll
            for (int l = 0; l < BSL; l++)
                gl2lds16(Bbase + (size_t)soffB[l] + k0, &smem[nb + 16384 + (wave * BSL + l) * 1024]);
            // wait for stage(t) only; stage(t+1)'s NDMA loads stay in flight
            if (BN == 128) asm volatile("s_waitcnt vmcnt(8)" ::: "memory");
            else           asm volatile("s_waitcnt vmcnt(6)" ::: "memory");
        } else {
            asm volatile("s_waitcnt vmcnt(0)" ::: "memory");
        }
        // barrier 2: cross-wave visibility of the landed tile
        __builtin_amdgcn_s_barrier();
        asm volatile("" ::: "memory");

#pragma unroll
        for (int s2 = 0; s2 < 2; s2++) {
            short8 af[4], bfr[BSL];
            int c = s2 * 4 + quad;
#pragma unroll
            for (int i = 0; i < 4; i++) {
                int row = wm * 64 + i * 16 + l15;
                af[i] = *(const short8*)(&smem[cb + row * 128 + ((c ^ (row & 7)) * 16)]);
            }
#pragma unroll
            for (int j = 0; j < BSL; j++) {
                int row = wn * (BN / 2) + j * 16 + l15;
                bfr[j] = *(const short8*)(&smem[cb + 16384 + row * 128 + ((c ^ (row & 7)) * 16)]);
            }
#pragma unroll
            for (int i = 0; i < 4; i++)
#pragma unroll
                for (int j = 0; j < BSL; j++)
                    acc[i][j] = MFMA32(af[i], bfr[j], acc[i][j]);
        }
    }

#pragma unroll
    for (int i = 0; i < 4; i++) {
#pragma unroll
        for (int j = 0; j < BSL; j++) {
            int n = bn * BN + wn * (BN / 2) + j * 16 + l15;
#pragma unroll
            for (int r = 0; r < 4; r++) {
                int m = bm * 128 + wm * 64 + i * 16 + quad * 4 + r;
                float fv = acc[i][j][r];
                if (MODE == 1) {
                    outf[(size_t)m * N + n] = fv;
                } else {
                    int t = n >> 10;            // 0=q 1=k 2=v
                    int h = (n >> 6) & 15;
                    int d = n & 63;
                    int b = m >> 11, si = m & 2047;
                    if (t == 2) {
                        // V^T with key interleave within 32-groups
                        int sip = (si & ~31) | (((si >> 2) & 3) << 3)
                                | (((si >> 4) & 1) << 2) | (si & 3);
                        out2[(((size_t)(b * 16 + h)) * 64 + d) * 2048 + sip] = f2bf(fv);
                    } else {
                        // q pre-scaled by 0.125*log2(e) (softmax fold)
                        if (t == 0) fv *= 0.18033688f;
                        size_t off = (((size_t)(b * 16 + h)) * 2048 + si) * 64 + d;
                        unsigned short* dst = (t == 0) ? out0 : out1;
                        dst[off] = f2bf(fv);
                    }
                }
            }
        }
    }
}

// ---------------------------------------------------------------------------
// Flash attention v11 — q-split waves + BLOCK-SHARED staged K/V double-buffer.
// Round-3 lesson: direct-global reads let the compiler serialize loads
// (VGPR=44, every pipe <8%). Latency hiding must be structural: use the
// proven gl2lds + raw-barrier + counted-vmcnt pipeline (round-1 gemm/attn).
// Round-3 keeps: q-split (wave owns 16 q-rows, iterates ALL keys) -> o[4]
// accumulator (16 VGPRs), complete per-wave softmax denominator, NO
// cross-wave reduction, NO epilogue LDS.
// New: all 4 waves share one staged 8KB K/V chunk per iter (each wave issues
// just 2 DMAs), LDS = 2 x 8KB = 16KB -> 4 blocks/CU (grid-limited), ~50%
// occupancy, and 4x less global K/V traffic than round-3.
// vmcnt(2) per wave: outstanding = stage(t)[2] + mf[2] + stage(t+1)[2];
// waiting to 2 retires stage(t)+mf in order, keeps stage(t+1) in flight.
//  * full-K=32 PV via key-interleaved V^T (one un-padded MFMA per dt)
//  * mask addend in QK MFMA C-init; Q pre-scaled by 0.125*log2e -> exp2
//    directly on MFMA output.
// ---------------------------------------------------------------------------
__global__ __launch_bounds__(256, 4)
void attn_kernel(const unsigned short* __restrict__ Qb,
                 const unsigned short* __restrict__ Kb,
                 const unsigned short* __restrict__ VbT,
                 const float* __restrict__ m2b,
                 const float* __restrict__ gateb,
                 unsigned short* __restrict__ ctx)
{
    __shared__ unsigned char smem[16384];        // 2 x (K 4KB + V 4KB)
    const int S = 2048;
    const int tid  = threadIdx.x;
    const int wave = tid >> 6, lane = tid & 63;
    const int l15  = lane & 15, quad = lane >> 4;

    int Lid = blockIdx.y * gridDim.x + blockIdx.x;
    int bh = (Lid & 7) * 4 + ((Lid >> 3) & 3);
    int qc = Lid >> 5;
    const int b = bh >> 4, h = bh & 15;
    const int q0 = qc * 64 + wave * 16;          // this wave's 16 q-rows

    const size_t headoff = (size_t)bh * S * 64;
    const unsigned short* Qh  = Qb  + headoff;   // [S][64] (pre-scaled)
    const unsigned short* Kh  = Kb  + headoff;   // [S][64]
    const unsigned short* VhT = VbT + headoff;   // [64][S'] key-interleaved
    const float* m2p = m2b + (size_t)b * S;

    // staging offsets: this wave stages quarter w of each 4KB section
    // (s = wave*64 + lane; K: [32key][64d] swizzled, V: [64d][32k'] swizzled)
    int koff, voff;
    {
        int s = wave * 64 + lane;
        int key = s >> 3;
        koff = key * 64 + (((s & 7) ^ (key & 7)) * 8);
        int d = s >> 2;
        voff = d * 2048 + (((s & 3) ^ (d & 3)) * 8);
    }
    // LDS read offsets (within current buffer)
    int qkoff[2];
#pragma unroll
    for (int s2 = 0; s2 < 2; s2++)
        qkoff[s2] = l15 * 128 + (((s2 * 4 + quad) ^ (l15 & 7)) * 16);
    const int pvoff = 4096 + l15 * 64 + ((quad ^ (l15 & 3)) * 16);

    // Q B-frags for this wave's rows: aq[s2] = Q[q0+l15][s2*32+quad*8+j]
    short8 aq[2];
#pragma unroll
    for (int s2 = 0; s2 < 2; s2++)
        aq[s2] = *(const short8*)(Qh + (size_t)(q0 + l15) * 64 + s2 * 32 + quad * 8);

    floatx4 o[4];                    // O^T partial [dt]  (d = dt*16+quad*4+r)
    floatx4 lq = floatx4{0.f, 0.f, 0.f, 0.f};
#pragma unroll
    for (int dt = 0; dt < 4; dt++) o[dt] = floatx4{0.f, 0.f, 0.f, 0.f};

    const uint4v onesu = {0x3F803F80u, 0x3F803F80u, 0x3F803F80u, 0x3F803F80u};
    const short8 ONES = __builtin_bit_cast(short8, onesu);

    // prologue: stage chunk 0 (keys 0..31) into buffer 0
    gl2lds16(Kh + koff, &smem[wave * 1024]);
    gl2lds16(VhT + voff, &smem[4096 + wave * 1024]);

    for (int i = 0; i < 64; i++) {
        const int cb = (i & 1) * 8192;
        const int nb = ((i + 1) & 1) * 8192;
        const int kb = i * 32;
        // mask addends (QK C-init: C/D row == key == quad*4+r)
        floatx4 mf[2];
#pragma unroll
        for (int t = 0; t < 2; t++)
            mf[t] = *(const floatx4*)(m2p + kb + t * 16 + quad * 4);
        asm volatile("" ::: "memory");
        // barrier 1: all waves done reading buf[nb] (iter i-1)
        __builtin_amdgcn_s_barrier();
        asm volatile("" ::: "memory");
        if (i + 1 < 64) {
            const int kbn = (i + 1) * 32;
            gl2lds16(Kh + (size_t)kbn * 64 + koff, &smem[nb + wave * 1024]);
            gl2lds16(VhT + kbn + voff, &smem[nb + 4096 + wave * 1024]);
            // retire stage(i)+mf (oldest 4); stage(i+1)'s 2 stay in flight
            asm volatile("s_waitcnt vmcnt(2)" ::: "memory");
        } else {
            asm volatile("s_waitcnt vmcnt(0)" ::: "memory");
        }
        // barrier 2: whole chunk i visible to all waves
        __builtin_amdgcn_s_barrier();
        asm volatile("" ::: "memory");

        // K frags from LDS
        short8 kf[2][2];
#pragma unroll
        for (int t = 0; t < 2; t++)
#pragma unroll
            for (int s2 = 0; s2 < 2; s2++)
                kf[t][s2] = *(const short8*)(&smem[cb + qkoff[s2] + t * 2048]);
        // V frags from LDS (interleaved key positions)
        short8 vf[4];
#pragma unroll
        for (int dt = 0; dt < 4; dt++)
            vf[dt] = *(const short8*)(&smem[cb + pvoff + dt * 1024]);

        // S^T = K·Q^T, C init = mask addend (log2 domain, fixed-max -10)
        floatx4 st0 = MFMA32(kf[0][0], aq[0], mf[0]);
        floatx4 st1 = MFMA32(kf[1][0], aq[0], mf[1]);
        st0 = MFMA32(kf[0][1], aq[1], st0);
        st1 = MFMA32(kf[1][1], aq[1], st1);
        // exp directly on MFMA output (Q pre-scaled, mask in C-init)
        float e00 = EXP2(st0[0]), e01 = EXP2(st0[1]);
        float e02 = EXP2(st0[2]), e03 = EXP2(st0[3]);
        float e10 = EXP2(st1[0]), e11 = EXP2(st1[1]);
        float e12 = EXP2(st1[2]), e13 = EXP2(st1[3]);
        // P packed across BOTH key-tiles in interleave order
        uint4v pu = {pack_bf2(e00, e01), pack_bf2(e02, e03),
                     pack_bf2(e10, e11), pack_bf2(e12, e13)};
        short8 pf = __builtin_bit_cast(short8, pu);
        // full-K=32 PV: one un-padded MFMA per dt + one l-row MFMA
#pragma unroll
        for (int dt = 0; dt < 4; dt++)
            o[dt] = MFMA32(vf[dt], pf, o[dt]);
        lq = MFMA32(ONES, pf, lq);
    }

    // epilogue: wave-complete softmax; lane writes q = q0 + l15, d block dt
    float iv = gateb[h] / lq[0];
    size_t base = ((size_t)(b * 2048 + q0 + l15)) * 1024 + h * 64 + quad * 4;
#pragma unroll
    for (int dt = 0; dt < 4; dt++) {
        uint2v w;
        w[0] = pack_bf2(o[dt][0] * iv, o[dt][1] * iv);
        w[1] = pack_bf2(o[dt][2] * iv, o[dt][3] * iv);
        *(uint2v*)(ctx + base + dt * 16) = w;
    }
}

// ---------------------------------------------------------------------------
extern "C" void kernel_launch(void* const* d_in, const int* in_sizes, int n_in,
                              void* d_out, int out_size, void* d_ws, size_t ws_size,
                              hipStream_t stream)
{
    const float* hidden = (const float*)d_in[0]; // [2,2048,1024] fp32
    const float* mask   = (const float*)d_in[1]; // [2,1,1,2048]  fp32
    const float* w_qkv  = (const float*)d_in[2]; // [3072,1024]   fp32
    const float* w_out  = (const float*)d_in[3]; // [1024,1024]   fp32
    const float* gate   = (const float*)d_in[4]; // [16]          fp32
    float* out = (float*)d_out;                  // [2,2048,1024] fp32

    unsigned short* q_buf = (unsigned short*)d_ws;   // [2,16,2048,64] bf16 (pre-scaled)
    unsigned short* k_buf = q_buf + 4194304;         // [2,16,2048,64]
    unsigned short* v_buf = k_buf + 4194304;         // [2,16,64,2048] (V^T, interleaved)
    unsigned short* c_buf = v_buf + 4194304;         // [2,2048,1024]  bf16
    unsigned short* h_bf  = c_buf + 4194304;         // hidden bf16
    unsigned short* wq_bf = h_bf  + 4194304;         // w_qkv bf16
    unsigned short* wo_bf = wq_bf + 3145728;         // w_out bf16
    float* m2_buf = (float*)(wo_bf + 1048576);       // [2,2048] fp32

    // one-pass prep: fp32->bf16 converts + mask transform
    cvt_all<<<8196, 256, 0, stream>>>(hidden, w_qkv, w_out, mask,
                                      h_bf, wq_bf, wo_bf, m2_buf);

    // QKV projection, scatter q(pre-scaled)/k/V^T(interleaved)
    gemm_nt<0, 128><<<dim3(24, 32), 256, 0, stream>>>(h_bf, wq_bf, q_buf, k_buf, v_buf, nullptr, 3072);
    // fused flash attention + gate -> ctx bf16 (64-q blocks, grid 1024)
    attn_kernel<<<dim3(32, 32), 256, 0, stream>>>(q_buf, k_buf, v_buf, m2_buf, gate, c_buf);
    // output projection -> out fp32 (grid 16x32, 128x64 tiles)
    gemm_nt<1, 64><<<dim3(16, 32), 256, 0, stream>>>(c_buf, wo_bf, nullptr, nullptr, nullptr, out, 1024);
}